// Round 11
// baseline (187.714 us; speedup 1.0000x reference)
//
#include <hip/hip_runtime.h>

// Problem constants (powers of two -> shift/mask index math)
// B=32, C=3, H=512, W=512; H*W = 2^18, W = 2^9
#define IMG_B 32
#define IMG_C 3
#define IMG_H 512
#define IMG_W 512
#define HW_SHIFT 18
#define W_SHIFT 9

// 2 px/thread: each block of 256 threads covers one full image row (512 px).
#define NBLOCKS_X IMG_H                   // 512 row-blocks per image
#define NPARTIALS (NBLOCKS_X * IMG_B)     // 16384 per-block partial sums

// d_ws layout: [0, 2304)         : 64 inverted 3x3 matrices (32 pred, 32 true), 9 floats each
//                                  rows 0/1 pre-scaled by 512/511 (normalization folded in)
//              [2304, 2304+64K)  : per-block float partial sums (no atomics)
#define WS_INV_FLOATS (64 * 9)
#define WS_PART_OFFSET (WS_INV_FLOATS * sizeof(float))

typedef float v2f __attribute__((ext_vector_type(2)));

__global__ void photoloss_invert_kernel(const float* __restrict__ Hp,
                                        const float* __restrict__ Ht,
                                        float* __restrict__ ws_inv) {
    int t = threadIdx.x;
    if (t < 64) {
        const float* src = (t < 32) ? (Hp + t * 9) : (Ht + (t - 32) * 9);
        float* dst = ws_inv + t * 9;
        // 3x3 inverse via adjugate, computed in double for conditioning.
        double a = src[0], b = src[1], c = src[2];
        double d = src[3], e = src[4], f = src[5];
        double g = src[6], h = src[7], i = src[8];
        double A = e * i - f * h;
        double Bc = c * h - b * i;
        double Cc = b * f - c * e;
        double D = f * g - d * i;
        double E = a * i - c * g;
        double F = c * d - a * f;
        double G = d * h - e * g;
        double Hh = b * g - a * h;
        double Ii = a * e - b * d;
        double idet = 1.0 / (a * A + b * D + c * G);
        // Fold the grid-normalization chain into rows 0/1:
        // xs = ((2X/(W-1)-1+1)*W-1)*0.5 = X*(W/(W-1)) - 0.5
        const double sc = (double)IMG_W / (double)(IMG_W - 1);  // 512/511 (H==W)
        dst[0] = (float)(A * idet * sc);
        dst[1] = (float)(Bc * idet * sc);
        dst[2] = (float)(Cc * idet * sc);
        dst[3] = (float)(D * idet * sc);
        dst[4] = (float)(E * idet * sc);
        dst[5] = (float)(F * idet * sc);
        dst[6] = (float)(G * idet);
        dst[7] = (float)(Hh * idet);
        dst[8] = (float)(Ii * idet);
    }
}

// Paired-corner sampling setup (see R9 notes). E[0]/E[1] = clamped element
// indices of the (y0,y1) row pairs; Wv[0]/Wv[1] = packed (slotA,slotB)
// weights for row0/row1. Validity lives ONLY in the weights. Slot-swaps:
// left edge x0==-1 (x1 value in slot A) and clamp-down e==H*W-1 (x0 value
// in slot B). x/y-symmetric math packed into v2f (v_pk_* on gfx950).
__device__ __forceinline__ void grid_setup_pair(float X, float Y, float Z,
                                                int* E, v2f* Wv) {
    const float iz = __builtin_amdgcn_rcpf(Z);
    const v2f S = __builtin_elementwise_fma((v2f){X, Y}, (v2f){iz, iz},
                                            (v2f){-0.5f, -0.5f});
    const float x0f = __builtin_floorf(S.x);
    const float y0f = __builtin_floorf(S.y);
    const int x0 = (int)x0f, y0 = (int)y0f;
    const int x1 = x0 + 1, y1 = y0 + 1;

    const v2f w1 = S - (v2f){x0f, y0f};     // (wx1, wy1), one pk_add
    const v2f w0 = (v2f){1.0f, 1.0f} - w1;  // (wx0, wy0)
    const float wx0m = ((unsigned)x0 < (unsigned)IMG_W) ? w0.x : 0.0f;
    const float wx1m = ((unsigned)x1 < (unsigned)IMG_W) ? w1.x : 0.0f;
    const float wy0m = ((unsigned)y0 < (unsigned)IMG_H) ? w0.y : 0.0f;
    const float wy1m = ((unsigned)y1 < (unsigned)IMG_H) ? w1.y : 0.0f;

    const bool sl = (x0 < 0);               // x0==-1 => x1 corner in slot A
    const float xA = sl ? wx1m : wx0m;      // (x0<=-2 => wx1m==0 too)
    const float xB = sl ? 0.0f : wx1m;
    const int xc0 = min(max(x0, 0), IMG_W - 1);

    const int e0r = y0 * IMG_W + xc0;       // may be far out of range
    const int e1r = e0r + IMG_W;
    const int emax = IMG_H * IMG_W - 2;     // pair [emax, emax+1] is last valid
    const int e0 = min(max(e0r, 0), emax);
    const int e1 = min(max(e1r, 0), emax);
    // Clamp fired? Either y-invalid (y-weight 0, slots irrelevant) or the
    // genuine e==H*W-1 corner case (clamp-down by 1: x0 value in slot B).
    const bool d0 = (e0 != e0r);
    const bool d1 = (e1 != e1r);
    const v2f xw0 = d0 ? (v2f){0.0f, xA} : (v2f){xA, xB};
    const v2f xw1 = d1 ? (v2f){0.0f, xA} : (v2f){xA, xB};

    E[0] = e0;
    E[1] = e1;
    Wv[0] = xw0 * (v2f){wy0m, wy0m};        // pk_mul
    Wv[1] = xw1 * (v2f){wy1m, wy1m};        // pk_mul
}

// 8-byte load at 4-byte alignment: memcpy -> load <2 x float> align 4 ->
// global_load_dwordx2 (gfx950 supports unaligned global access; MUBUF
// dwordx2 does NOT -- that broke R8).
__device__ __forceinline__ v2f load_pair(const float* p) {
    v2f r;
    __builtin_memcpy(&r, p, 8);
    return r;
}

// 2 px/thread; __launch_bounds__(256,4) caps VGPR at 128 (4 waves/EU).
__global__ __launch_bounds__(256, 4) void photoloss_main_kernel(
        const float* __restrict__ I,
        const float* __restrict__ ws_inv,
        float* __restrict__ partials) {
    const int b = blockIdx.y;
    const int row = blockIdx.x;            // one full image row per block
    const int t = threadIdx.x;
    const float fy = (float)row;
    const float fx0 = (float)t;
    const float fx1 = (float)(t + 256);

    const float* __restrict__ hp = ws_inv + b * 9;          // pred inverse (rows 0/1 pre-scaled)
    const float* __restrict__ ht = ws_inv + (b + 32) * 9;   // true inverse

    // y-dependent part of each homography row is shared by both pixels
    const float cxp = __builtin_fmaf(hp[1], fy, hp[2]);
    const float cyp = __builtin_fmaf(hp[4], fy, hp[5]);
    const float czp = __builtin_fmaf(hp[7], fy, hp[8]);
    const float cxt = __builtin_fmaf(ht[1], fy, ht[2]);
    const float cyt = __builtin_fmaf(ht[4], fy, ht[5]);
    const float czt = __builtin_fmaf(ht[7], fy, ht[8]);

    // combo j: 0=px0-pred, 1=px0-true, 2=px1-pred, 3=px1-true
    int Eoff[8];      // [2j] = row-y0 pair element index, [2j+1] = row-y1
    v2f Wv[8];        // [2j+rr] = packed (slotA,slotB) weights for that row
    grid_setup_pair(__builtin_fmaf(hp[0], fx0, cxp), __builtin_fmaf(hp[3], fx0, cyp),
                    __builtin_fmaf(hp[6], fx0, czp), Eoff + 0, Wv + 0);
    grid_setup_pair(__builtin_fmaf(ht[0], fx0, cxt), __builtin_fmaf(ht[3], fx0, cyt),
                    __builtin_fmaf(ht[6], fx0, czt), Eoff + 2, Wv + 2);
    grid_setup_pair(__builtin_fmaf(hp[0], fx1, cxp), __builtin_fmaf(hp[3], fx1, cyp),
                    __builtin_fmaf(hp[6], fx1, czp), Eoff + 4, Wv + 4);
    grid_setup_pair(__builtin_fmaf(ht[0], fx1, cxt), __builtin_fmaf(ht[3], fx1, cyt),
                    __builtin_fmaf(ht[6], fx1, czt), Eoff + 6, Wv + 6);

    // Per-pair predicate: weights are nonneg, sum==0 -> pair contributes v*0
    // only -> skip its loads. EXEC-masked lanes generate NO TA requests, and
    // the gather path is per-dword/line throughput-bound (~4 dwords/cyc/CU,
    // R9/R10 measured). One predicate serves all 3 channels.
    bool pred[8];
#pragma unroll
    for (int k = 0; k < 8; ++k)
        pred[k] = (Wv[k].x + Wv[k].y) > 0.0f;

    float lsum = 0.0f;
    const bool anyp = pred[0] | pred[1] | pred[2] | pred[3]
                    | pred[4] | pred[5] | pred[6] | pred[7];
    // Whole-wave dead skip: fully-OOB waves (both warps) skip loads AND the
    // FMA epilogue entirely.
    if (__ballot(anyp) != 0ull) {
        const float* __restrict__ ch0 = I + ((size_t)b * IMG_C << HW_SHIFT);
        const float* __restrict__ ch1 = ch0 + ((size_t)1 << HW_SHIFT);
        const float* __restrict__ ch2 = ch0 + ((size_t)2 << HW_SHIFT);

        v2f r[24];
#pragma unroll
        for (int k = 0; k < 8; ++k) {
            v2f v0 = (v2f){0.0f, 0.0f};
            v2f v1 = v0;
            v2f v2 = v0;
            if (pred[k]) {
                v0 = load_pair(ch0 + Eoff[k]);
                v1 = load_pair(ch1 + Eoff[k]);
                v2 = load_pair(ch2 + Eoff[k]);
            }
            r[0 * 8 + k] = v0;
            r[1 * 8 + k] = v1;
            r[2 * 8 + k] = v2;
        }

#pragma unroll
        for (int c = 0; c < IMG_C; ++c) {
            const v2f* rc = r + c * 8;
            // packed weight-FMAs (v_pk_fma_f32), then horizontal adds
            v2f ap0 = __builtin_elementwise_fma(rc[1], Wv[1], rc[0] * Wv[0]);
            v2f at0 = __builtin_elementwise_fma(rc[3], Wv[3], rc[2] * Wv[2]);
            v2f ap1 = __builtin_elementwise_fma(rc[5], Wv[5], rc[4] * Wv[4]);
            v2f at1 = __builtin_elementwise_fma(rc[7], Wv[7], rc[6] * Wv[6]);
            const float d0 = (ap0.x + ap0.y) - (at0.x + at0.y);
            const float d1 = (ap1.x + ap1.y) - (at1.x + at1.y);
            lsum = __builtin_fmaf(d0, d0, lsum);
            lsum = __builtin_fmaf(d1, d1, lsum);
        }
    }

    // wave (64-lane) reduction
#pragma unroll
    for (int off = 32; off > 0; off >>= 1)
        lsum += __shfl_down(lsum, off, 64);

    __shared__ float wsum[4];
    const int lane = threadIdx.x & 63;
    const int wid = threadIdx.x >> 6;
    if (lane == 0) wsum[wid] = lsum;
    __syncthreads();
    if (threadIdx.x == 0) {
        // One coalesced store per block -- NO atomics (same-address fp64
        // atomicAdd serialized the whole grid at ~400 us in R1/R2).
        partials[blockIdx.y * gridDim.x + blockIdx.x] = wsum[0] + wsum[1] + wsum[2] + wsum[3];
    }
}

__global__ __launch_bounds__(1024) void photoloss_reduce_kernel(
        const float* __restrict__ partials, float* __restrict__ out) {
    // Single block, 1024 threads = 16 waves; 16 partials per thread.
    double s = 0.0;
    for (int i = threadIdx.x; i < NPARTIALS; i += 1024)
        s += (double)partials[i];
#pragma unroll
    for (int off = 32; off > 0; off >>= 1)
        s += __shfl_down(s, off, 64);

    __shared__ double wsum[16];
    const int lane = threadIdx.x & 63;
    const int wid = threadIdx.x >> 6;
    if (lane == 0) wsum[wid] = s;
    __syncthreads();
    if (threadIdx.x == 0) {
        double total = 0.0;
#pragma unroll
        for (int i = 0; i < 16; ++i) total += wsum[i];
        const double n = (double)IMG_B * IMG_C * IMG_H * IMG_W;  // 25165824
        out[0] = (float)(total / n);
    }
}

extern "C" void kernel_launch(void* const* d_in, const int* in_sizes, int n_in,
                              void* d_out, int out_size, void* d_ws, size_t ws_size,
                              hipStream_t stream) {
    const float* Hp = (const float*)d_in[0];
    const float* Ht = (const float*)d_in[1];
    const float* I  = (const float*)d_in[2];
    float* out = (float*)d_out;

    float* ws_inv = (float*)d_ws;
    float* partials = (float*)((char*)d_ws + WS_PART_OFFSET);

    photoloss_invert_kernel<<<1, 64, 0, stream>>>(Hp, Ht, ws_inv);

    dim3 grid(NBLOCKS_X, IMG_B);  // (512, 32), natural order (R6 XCD swizzle regressed)
    photoloss_main_kernel<<<grid, 256, 0, stream>>>(I, ws_inv, partials);

    photoloss_reduce_kernel<<<1, 1024, 0, stream>>>(partials, out);
}